// Round 1
// baseline (686.491 us; speedup 1.0000x reference)
//
#include <hip/hip_runtime.h>
#include <math.h>

#define T_TOTAL 2048
#define NB 16
#define D 256
#define T0 1696      // h buffer covers t in [1696, 2047]
#define TBUF 352
#define TSKIP 1952   // skip needed for t in [1952, 2047]
#define LOUT 96

#define BM 64
#define BN 64
#define BK 32
#define APAD 4

// ---------------- up-projection: h0[t,b,:] = concat(x_lag,x_cov) @ up_W + up_b
__global__ void up_kernel(const float* __restrict__ x_lag,
                          const float* __restrict__ x_cov,
                          const float* __restrict__ up_W,
                          const float* __restrict__ up_b,
                          float* __restrict__ h)
{
    int bid = blockIdx.x;          // 0 .. TBUF*NB-1
    int tt  = bid >> 4;
    int b   = bid & 15;
    int t   = T0 + tt;
    int c   = threadIdx.x;         // 0..255
    float acc = up_b[c] + x_lag[t * NB + b] * up_W[c];
    const float* cov = &x_cov[(t * NB + b) * 7];
    #pragma unroll
    for (int j = 0; j < 7; ++j)
        acc += cov[j] * up_W[(j + 1) * D + c];
    h[((size_t)bid << 8) + c] = acc;
}

// ---------------- per-layer weight transpose into GEMM-friendly layout
// wT[k][co]  k = tap*256 + ci (512x512);  w2T[ci][co] (256x512)
__global__ void transpose_w(const float* __restrict__ dil_w_i,
                            const float* __restrict__ skip_w_i,
                            float* __restrict__ wT,
                            float* __restrict__ w2T)
{
    int n = blockIdx.x * 256 + threadIdx.x;
    if (n < 512 * 512) {
        int k = n >> 9, co = n & 511;
        wT[n] = dil_w_i[((size_t)co << 9) + ((k & 255) << 1) + (k >> 8)];
    } else {
        int n2 = n - 512 * 512;
        int ci = n2 >> 9, co = n2 & 511;
        w2T[n2] = skip_w_i[((size_t)co << 8) + ci];
    }
}

// ---------------- GEMM1: z = [h(t-dil), h(t)] @ wT ; gated = tanh(f)*sigmoid(g)
__global__ __launch_bounds__(256) void gemm_gate(
    const float* __restrict__ h, float* __restrict__ gated,
    const float* __restrict__ wT, const float* __restrict__ bias,
    int tb, int dil, int M)
{
    __shared__ float As[BK][BM + APAD];
    __shared__ float Wf[BK][BN];
    __shared__ float Wg[BK][BN];
    int tid = threadIdx.x;
    int m0 = blockIdx.x * BM;
    int cb = blockIdx.y * BN;     // 0..255 (f-half col base)
    int ty = tid >> 4, tx = tid & 15;
    float accf[4][4] = {{0.f}}, accg[4][4] = {{0.f}};

    for (int k0 = 0; k0 < 512; k0 += BK) {
        // stage A (64 x 32), transposed into As[k][m]
        #pragma unroll
        for (int l = 0; l < 2; ++l) {
            int li = tid + l * 256;
            int arow = li >> 3, kq = li & 7;
            int m = m0 + arow; if (m >= M) m = M - 1;
            int t = tb + (m >> 4);
            int b = m & 15;
            int ts = (k0 >= 256) ? t : t - dil;
            int ci = (k0 & 255) + (kq << 2);
            float4 a = *(const float4*)&h[((size_t)(((ts - T0) << 4) + b) << 8) + ci];
            As[(kq << 2) + 0][arow] = a.x;
            As[(kq << 2) + 1][arow] = a.y;
            As[(kq << 2) + 2][arow] = a.z;
            As[(kq << 2) + 3][arow] = a.w;
        }
        // stage W tiles (32 x 64 each)
        #pragma unroll
        for (int l = 0; l < 2; ++l) {
            int li = tid + l * 256;
            int wrow = li >> 4, cq = li & 15;
            const float* base = &wT[(size_t)(k0 + wrow) * 512 + cb + (cq << 2)];
            *(float4*)&Wf[wrow][cq << 2] = *(const float4*)base;
            *(float4*)&Wg[wrow][cq << 2] = *(const float4*)(base + 256);
        }
        __syncthreads();
        #pragma unroll
        for (int kk = 0; kk < BK; ++kk) {
            const float4 a4 = *(const float4*)&As[kk][ty << 2];
            const float4 f4 = *(const float4*)&Wf[kk][tx << 2];
            const float4 g4 = *(const float4*)&Wg[kk][tx << 2];
            const float av[4] = {a4.x, a4.y, a4.z, a4.w};
            const float fv[4] = {f4.x, f4.y, f4.z, f4.w};
            const float gv[4] = {g4.x, g4.y, g4.z, g4.w};
            #pragma unroll
            for (int i = 0; i < 4; ++i)
                #pragma unroll
                for (int j = 0; j < 4; ++j) {
                    accf[i][j] = fmaf(av[i], fv[j], accf[i][j]);
                    accg[i][j] = fmaf(av[i], gv[j], accg[i][j]);
                }
        }
        __syncthreads();
    }
    // epilogue: gating
    #pragma unroll
    for (int i = 0; i < 4; ++i) {
        int m = m0 + (ty << 2) + i;
        if (m < M) {
            float ov[4];
            #pragma unroll
            for (int j = 0; j < 4; ++j) {
                int co = cb + (tx << 2) + j;
                float fv = accf[i][j] + bias[co];
                float gv = accg[i][j] + bias[co + 256];
                ov[j] = tanhf(fv) * (1.0f / (1.0f + expf(-gv)));
            }
            float4 o; o.x = ov[0]; o.y = ov[1]; o.z = ov[2]; o.w = ov[3];
            *(float4*)&gated[((size_t)m << 8) + cb + (tx << 2)] = o;
        }
    }
}

// ---------------- GEMM2: z2 = gated @ w2T ; h += z2[:,:256]; skip (+)= z2[:,256:]
__global__ __launch_bounds__(256) void gemm_skip(
    const float* __restrict__ gated, const float* __restrict__ w2T,
    float* __restrict__ h, float* __restrict__ skip,
    const float* __restrict__ bias, int tb, int M, int first)
{
    __shared__ float As[BK][BM + APAD];
    __shared__ float Wh[BK][BN];
    __shared__ float Ws[BK][BN];
    int tid = threadIdx.x;
    int m0 = blockIdx.x * BM;
    int cb = blockIdx.y * BN;     // 0..255
    int ty = tid >> 4, tx = tid & 15;
    float acch[4][4] = {{0.f}}, accs[4][4] = {{0.f}};

    for (int k0 = 0; k0 < 256; k0 += BK) {
        #pragma unroll
        for (int l = 0; l < 2; ++l) {
            int li = tid + l * 256;
            int arow = li >> 3, kq = li & 7;
            int m = m0 + arow; if (m >= M) m = M - 1;
            float4 a = *(const float4*)&gated[((size_t)m << 8) + k0 + (kq << 2)];
            As[(kq << 2) + 0][arow] = a.x;
            As[(kq << 2) + 1][arow] = a.y;
            As[(kq << 2) + 2][arow] = a.z;
            As[(kq << 2) + 3][arow] = a.w;
        }
        #pragma unroll
        for (int l = 0; l < 2; ++l) {
            int li = tid + l * 256;
            int wrow = li >> 4, cq = li & 15;
            const float* base = &w2T[(size_t)(k0 + wrow) * 512 + cb + (cq << 2)];
            *(float4*)&Wh[wrow][cq << 2] = *(const float4*)base;
            *(float4*)&Ws[wrow][cq << 2] = *(const float4*)(base + 256);
        }
        __syncthreads();
        #pragma unroll
        for (int kk = 0; kk < BK; ++kk) {
            const float4 a4 = *(const float4*)&As[kk][ty << 2];
            const float4 h4 = *(const float4*)&Wh[kk][tx << 2];
            const float4 s4 = *(const float4*)&Ws[kk][tx << 2];
            const float av[4] = {a4.x, a4.y, a4.z, a4.w};
            const float hv[4] = {h4.x, h4.y, h4.z, h4.w};
            const float sv[4] = {s4.x, s4.y, s4.z, s4.w};
            #pragma unroll
            for (int i = 0; i < 4; ++i)
                #pragma unroll
                for (int j = 0; j < 4; ++j) {
                    acch[i][j] = fmaf(av[i], hv[j], acch[i][j]);
                    accs[i][j] = fmaf(av[i], sv[j], accs[i][j]);
                }
        }
        __syncthreads();
    }
    #pragma unroll
    for (int i = 0; i < 4; ++i) {
        int m = m0 + (ty << 2) + i;
        if (m < M) {
            int t = tb + (m >> 4);
            int b = m & 15;
            int col = cb + (tx << 2);
            size_t hidx = ((size_t)(((t - T0) << 4) + b) << 8) + col;
            float4 hv = *(const float4*)&h[hidx];
            hv.x += acch[i][0] + bias[col + 0];
            hv.y += acch[i][1] + bias[col + 1];
            hv.z += acch[i][2] + bias[col + 2];
            hv.w += acch[i][3] + bias[col + 3];
            *(float4*)&h[hidx] = hv;
            if (t >= TSKIP) {
                size_t sidx = ((size_t)(((t - TSKIP) << 4) + b) << 8) + col;
                float4 sv;
                sv.x = accs[i][0] + bias[256 + col + 0];
                sv.y = accs[i][1] + bias[256 + col + 1];
                sv.z = accs[i][2] + bias[256 + col + 2];
                sv.w = accs[i][3] + bias[256 + col + 3];
                if (!first) {
                    float4 old = *(const float4*)&skip[sidx];
                    sv.x += old.x; sv.y += old.y; sv.z += old.z; sv.w += old.w;
                }
                *(float4*)&skip[sidx] = sv;
            }
        }
    }
}

// ---------------- final: out[b,l] = (skip[l,b,:] . loc_W + loc_b)*proj_W + proj_b
__global__ void final_kernel(const float* __restrict__ skip,
                             const float* __restrict__ loc_W,
                             const float* __restrict__ loc_b,
                             const float* __restrict__ proj_W,
                             const float* __restrict__ proj_b,
                             float* __restrict__ out)
{
    int tid = threadIdx.x;
    int w = tid >> 6, lane = tid & 63;
    int o = blockIdx.x * 4 + w;          // o = l*16 + b
    int l = o >> 4, b = o & 15;
    float4 s4 = *(const float4*)&skip[((size_t)o << 8) + (lane << 2)];
    float4 w4 = *(const float4*)&loc_W[lane << 2];
    float s = s4.x * w4.x + s4.y * w4.y + s4.z * w4.z + s4.w * w4.w;
    #pragma unroll
    for (int off = 32; off; off >>= 1) s += __shfl_down(s, off);
    if (lane == 0)
        out[b * LOUT + l] = (s + loc_b[0]) * proj_W[0] + proj_b[0];
}

extern "C" void kernel_launch(void* const* d_in, const int* in_sizes, int n_in,
                              void* d_out, int out_size, void* d_ws, size_t ws_size,
                              hipStream_t stream)
{
    const float* x_lag  = (const float*)d_in[0];
    const float* x_cov  = (const float*)d_in[1];
    const float* up_W   = (const float*)d_in[2];
    const float* up_b   = (const float*)d_in[3];
    const float* dil_w  = (const float*)d_in[4];
    const float* dil_b  = (const float*)d_in[5];
    const float* skip_w = (const float*)d_in[6];
    const float* skip_b = (const float*)d_in[7];
    const float* loc_W  = (const float*)d_in[8];
    const float* loc_b  = (const float*)d_in[9];
    const float* proj_W = (const float*)d_in[10];
    const float* proj_b = (const float*)d_in[11];
    float* out = (float*)d_out;

    float* ws    = (float*)d_ws;
    float* h     = ws;                           // TBUF*NB*D
    float* gated = h + (size_t)TBUF * NB * D;    // TBUF*NB*D
    float* skip  = gated + (size_t)TBUF * NB * D;// LOUT*NB*D
    float* wT    = skip + (size_t)LOUT * NB * D; // 512*512
    float* w2T   = wT + 512 * 512;               // 256*512

    hipLaunchKernelGGL(up_kernel, dim3(TBUF * NB), dim3(D), 0, stream,
                       x_lag, x_cov, up_W, up_b, h);

    for (int i = 0; i < 8; ++i) {
        int dil = 1 << i;
        int tb  = T0 + 2 * dil;            // first t computed by this layer
        int M   = (T_TOTAL - tb) * NB;
        int mtiles = (M + BM - 1) / BM;
        hipLaunchKernelGGL(transpose_w, dim3(1536), dim3(256), 0, stream,
                           dil_w + (size_t)i * 512 * 512,
                           skip_w + (size_t)i * 512 * 256, wT, w2T);
        hipLaunchKernelGGL(gemm_gate, dim3(mtiles, 4), dim3(256), 0, stream,
                           h, gated, wT, dil_b + (size_t)i * 512, tb, dil, M);
        hipLaunchKernelGGL(gemm_skip, dim3(mtiles, 4), dim3(256), 0, stream,
                           gated, w2T, h, skip, skip_b + (size_t)i * 512, tb, M,
                           i == 0 ? 1 : 0);
    }
    hipLaunchKernelGGL(final_kernel, dim3(LOUT * NB / 4), dim3(256), 0, stream,
                       skip, loc_W, loc_b, proj_W, proj_b, out);
}

// Round 2
// 317.443 us; speedup vs baseline: 2.1626x; 2.1626x over previous
//
#include <hip/hip_runtime.h>
#include <math.h>
#include <stdint.h>

#define T_TOTAL 2048
#define NB 16
#define D 256
#define T0 1696      // h buffer covers t in [1696, 2047]
#define TBUF 352
#define TSKIP 1952   // skip needed for t in [1952, 2047]
#define LOUT 96

typedef __bf16 bf16x8 __attribute__((ext_vector_type(8)));
typedef float f32x4 __attribute__((ext_vector_type(4)));

__device__ __forceinline__ void gload_lds16(const void* src, void* lds_dst) {
    auto g = (const __attribute__((address_space(1))) void*)(uintptr_t)src;
    auto l = (__attribute__((address_space(3))) void*)(uintptr_t)(
                 (uint32_t)(uintptr_t)lds_dst);
    __builtin_amdgcn_global_load_lds(g, l, 16, 0, 0);
}

// ---------------- weight prep: wT[i][co][k]=dil_w[i][co][ci][tap] (k=tap*256+ci)
//                  w2[i][co][ci]=skip_w[i][co][ci]   (both bf16)
__global__ void prep_w(const float* __restrict__ dil_w,
                       const float* __restrict__ skip_w,
                       __bf16* __restrict__ wT, __bf16* __restrict__ w2)
{
    int n = blockIdx.x * 256 + threadIdx.x;
    if (n < 8 * 512 * 512) {
        int i = n >> 18;
        int r = n & 262143;
        int co = r >> 9, k = r & 511;
        wT[n] = (__bf16)dil_w[(((size_t)(i << 9) + co) * 256 + (k & 255)) * 2 + (k >> 8)];
    } else {
        int n2 = n - 8 * 512 * 512;
        if (n2 < 8 * 512 * 256) w2[n2] = (__bf16)skip_w[n2];
    }
}

// ---------------- up-projection
__global__ void up_kernel(const float* __restrict__ x_lag,
                          const float* __restrict__ x_cov,
                          const float* __restrict__ up_W,
                          const float* __restrict__ up_b,
                          float* __restrict__ hf, __bf16* __restrict__ hb)
{
    int bid = blockIdx.x;          // 0 .. TBUF*NB-1
    int tt  = bid >> 4;
    int b   = bid & 15;
    int t   = T0 + tt;
    int c   = threadIdx.x;         // 0..255
    float acc = up_b[c] + x_lag[t * NB + b] * up_W[c];
    const float* cov = &x_cov[(t * NB + b) * 7];
    #pragma unroll
    for (int j = 0; j < 7; ++j)
        acc += cov[j] * up_W[(j + 1) * D + c];
    size_t idx = ((size_t)bid << 8) + c;
    hf[idx] = acc;
    hb[idx] = (__bf16)acc;
}

// ---------------- GEMM1 (MFMA): z = [h(t-dil),h(t)] @ wT^T ; gated=tanh(f)*sig(g)
__global__ __launch_bounds__(256) void gemm_gate(
    const __bf16* __restrict__ hb, __bf16* __restrict__ gated,
    const __bf16* __restrict__ wTl, const float* __restrict__ bias,
    int tb, int dil, int M)
{
    __shared__ __align__(16) unsigned char lds[32768];
    const int tid = threadIdx.x;
    const int lane = tid & 63, wid = tid >> 6;
    const int wm = wid >> 1, wn = wid & 1;
    const int m0 = blockIdx.x << 7;
    const int cb = blockIdx.y << 6;
    const int lr = lane >> 3;
    const int swzc = ((lane & 7) ^ lr) << 3;   // elems (16B units)
    const int l15 = lane & 15, l4 = lane >> 4;

    f32x4 accf[4][2] = {}; f32x4 accg[4][2] = {};
    const int roff1 = (tb - T0) * 16;
    const int roff0 = roff1 - dil * 16;

    for (int k0 = 0; k0 < 512; k0 += 64) {
        const int ci0 = k0 & 255;
        const int roff = (k0 < 256) ? roff0 : roff1;
        #pragma unroll
        for (int j = 0; j < 4; ++j) {
            int qa = (wid << 2) + j;
            gload_lds16(hb + (size_t)(m0 + (qa << 3) + lr + roff) * 256 + ci0 + swzc,
                        lds + (qa << 10));
        }
        #pragma unroll
        for (int j = 0; j < 2; ++j) {
            int qb = (wid << 1) + j;
            gload_lds16(wTl + (size_t)(cb + (qb << 3) + lr) * 512 + k0 + swzc,
                        lds + 16384 + (qb << 10));
            gload_lds16(wTl + (size_t)(cb + 256 + (qb << 3) + lr) * 512 + k0 + swzc,
                        lds + 24576 + (qb << 10));
        }
        __syncthreads();
        #pragma unroll
        for (int ks = 0; ks < 2; ++ks) {
            const int kb = (ks << 6) + (l4 << 4);
            bf16x8 av[4], bfv[2], bgv[2];
            #pragma unroll
            for (int fm = 0; fm < 4; ++fm) {
                int r = (wm << 6) + (fm << 4) + l15;
                av[fm] = *(const bf16x8*)(lds + r * 128 + (kb ^ ((r & 7) << 4)));
            }
            #pragma unroll
            for (int fn = 0; fn < 2; ++fn) {
                int n = (wn << 5) + (fn << 4) + l15;
                int o = n * 128 + (kb ^ ((n & 7) << 4));
                bfv[fn] = *(const bf16x8*)(lds + 16384 + o);
                bgv[fn] = *(const bf16x8*)(lds + 24576 + o);
            }
            #pragma unroll
            for (int fm = 0; fm < 4; ++fm)
                #pragma unroll
                for (int fn = 0; fn < 2; ++fn) {
                    accf[fm][fn] = __builtin_amdgcn_mfma_f32_16x16x32_bf16(
                        av[fm], bfv[fn], accf[fm][fn], 0, 0, 0);
                    accg[fm][fn] = __builtin_amdgcn_mfma_f32_16x16x32_bf16(
                        av[fm], bgv[fn], accg[fm][fn], 0, 0, 0);
                }
        }
        __syncthreads();
    }
    #pragma unroll
    for (int fm = 0; fm < 4; ++fm) {
        #pragma unroll
        for (int fn = 0; fn < 2; ++fn) {
            int c = cb + (wn << 5) + (fn << 4) + l15;
            float bfb = bias[c], bgb = bias[c + 256];
            #pragma unroll
            for (int r = 0; r < 4; ++r) {
                int m = m0 + (wm << 6) + (fm << 4) + (l4 << 2) + r;
                if (m < M) {
                    float fv = accf[fm][fn][r] + bfb;
                    float gv = accg[fm][fn][r] + bgb;
                    gated[(size_t)m * 256 + c] =
                        (__bf16)(tanhf(fv) * (1.0f / (1.0f + expf(-gv))));
                }
            }
        }
    }
}

// ---------------- GEMM2 (MFMA): z2 = gated @ w2^T ; h += z2[:,:256]; skip += rest
__global__ __launch_bounds__(256) void gemm_skip(
    const __bf16* __restrict__ gated, const __bf16* __restrict__ w2l,
    float* __restrict__ hf, __bf16* __restrict__ hb,
    float* __restrict__ skip, const float* __restrict__ bias,
    int tb, int M, int first)
{
    __shared__ __align__(16) unsigned char lds[32768];
    const int tid = threadIdx.x;
    const int lane = tid & 63, wid = tid >> 6;
    const int wm = wid >> 1, wn = wid & 1;
    const int m0 = blockIdx.x << 7;
    const int cb = blockIdx.y << 6;
    const int lr = lane >> 3;
    const int swzc = ((lane & 7) ^ lr) << 3;
    const int l15 = lane & 15, l4 = lane >> 4;

    f32x4 acch[4][2] = {}; f32x4 accs[4][2] = {};

    for (int k0 = 0; k0 < 256; k0 += 64) {
        #pragma unroll
        for (int j = 0; j < 4; ++j) {
            int qa = (wid << 2) + j;
            gload_lds16(gated + (size_t)(m0 + (qa << 3) + lr) * 256 + k0 + swzc,
                        lds + (qa << 10));
        }
        #pragma unroll
        for (int j = 0; j < 2; ++j) {
            int qb = (wid << 1) + j;
            gload_lds16(w2l + (size_t)(cb + (qb << 3) + lr) * 256 + k0 + swzc,
                        lds + 16384 + (qb << 10));
            gload_lds16(w2l + (size_t)(cb + 256 + (qb << 3) + lr) * 256 + k0 + swzc,
                        lds + 24576 + (qb << 10));
        }
        __syncthreads();
        #pragma unroll
        for (int ks = 0; ks < 2; ++ks) {
            const int kb = (ks << 6) + (l4 << 4);
            bf16x8 av[4], bhv[2], bsv[2];
            #pragma unroll
            for (int fm = 0; fm < 4; ++fm) {
                int r = (wm << 6) + (fm << 4) + l15;
                av[fm] = *(const bf16x8*)(lds + r * 128 + (kb ^ ((r & 7) << 4)));
            }
            #pragma unroll
            for (int fn = 0; fn < 2; ++fn) {
                int n = (wn << 5) + (fn << 4) + l15;
                int o = n * 128 + (kb ^ ((n & 7) << 4));
                bhv[fn] = *(const bf16x8*)(lds + 16384 + o);
                bsv[fn] = *(const bf16x8*)(lds + 24576 + o);
            }
            #pragma unroll
            for (int fm = 0; fm < 4; ++fm)
                #pragma unroll
                for (int fn = 0; fn < 2; ++fn) {
                    acch[fm][fn] = __builtin_amdgcn_mfma_f32_16x16x32_bf16(
                        av[fm], bhv[fn], acch[fm][fn], 0, 0, 0);
                    accs[fm][fn] = __builtin_amdgcn_mfma_f32_16x16x32_bf16(
                        av[fm], bsv[fn], accs[fm][fn], 0, 0, 0);
                }
        }
        __syncthreads();
    }
    const int roff = (tb - T0) * 16;
    const int ms0 = (TSKIP - tb) * 16;
    const int soff = (tb - TSKIP) * 16;
    #pragma unroll
    for (int fm = 0; fm < 4; ++fm) {
        #pragma unroll
        for (int fn = 0; fn < 2; ++fn) {
            int c = cb + (wn << 5) + (fn << 4) + l15;
            float bhb = bias[c], bsb = bias[c + 256];
            #pragma unroll
            for (int r = 0; r < 4; ++r) {
                int m = m0 + (wm << 6) + (fm << 4) + (l4 << 2) + r;
                if (m < M) {
                    size_t hi = (size_t)(m + roff) * 256 + c;
                    float hv = hf[hi] + acch[fm][fn][r] + bhb;
                    hf[hi] = hv;
                    hb[hi] = (__bf16)hv;
                    if (m >= ms0) {
                        size_t si = (size_t)(m + soff) * 256 + c;
                        float sv = accs[fm][fn][r] + bsb;
                        if (!first) sv += skip[si];
                        skip[si] = sv;
                    }
                }
            }
        }
    }
}

// ---------------- final
__global__ void final_kernel(const float* __restrict__ skip,
                             const float* __restrict__ loc_W,
                             const float* __restrict__ loc_b,
                             const float* __restrict__ proj_W,
                             const float* __restrict__ proj_b,
                             float* __restrict__ out)
{
    int tid = threadIdx.x;
    int w = tid >> 6, lane = tid & 63;
    int o = blockIdx.x * 4 + w;          // o = l*16 + b
    int l = o >> 4, b = o & 15;
    float4 s4 = *(const float4*)&skip[((size_t)o << 8) + (lane << 2)];
    float4 w4 = *(const float4*)&loc_W[lane << 2];
    float s = s4.x * w4.x + s4.y * w4.y + s4.z * w4.z + s4.w * w4.w;
    #pragma unroll
    for (int off = 32; off; off >>= 1) s += __shfl_down(s, off);
    if (lane == 0)
        out[b * LOUT + l] = (s + loc_b[0]) * proj_W[0] + proj_b[0];
}

extern "C" void kernel_launch(void* const* d_in, const int* in_sizes, int n_in,
                              void* d_out, int out_size, void* d_ws, size_t ws_size,
                              hipStream_t stream)
{
    const float* x_lag  = (const float*)d_in[0];
    const float* x_cov  = (const float*)d_in[1];
    const float* up_W   = (const float*)d_in[2];
    const float* up_b   = (const float*)d_in[3];
    const float* dil_w  = (const float*)d_in[4];
    const float* dil_b  = (const float*)d_in[5];
    const float* skip_w = (const float*)d_in[6];
    const float* skip_b = (const float*)d_in[7];
    const float* loc_W  = (const float*)d_in[8];
    const float* loc_b  = (const float*)d_in[9];
    const float* proj_W = (const float*)d_in[10];
    const float* proj_b = (const float*)d_in[11];
    float* out = (float*)d_out;

    unsigned char* ws = (unsigned char*)d_ws;
    float*  hf   = (float*)ws;                                   // 5632*256 f32
    __bf16* hb   = (__bf16*)(ws + 5767168);                      // 5632*256 bf16
    __bf16* gated= (__bf16*)(ws + 5767168 + 2883584);            // 5632*256 bf16
    float*  skip = (float*)(ws + 5767168 + 2 * 2883584);         // 1536*256 f32
    __bf16* wT   = (__bf16*)(ws + 5767168 + 2 * 2883584 + 1572864);   // 8*512*512
    __bf16* w2   = (__bf16*)((unsigned char*)wT + 4194304);      // 8*512*256

    hipLaunchKernelGGL(prep_w, dim3(12288), dim3(256), 0, stream,
                       dil_w, skip_w, wT, w2);
    hipLaunchKernelGGL(up_kernel, dim3(TBUF * NB), dim3(D), 0, stream,
                       x_lag, x_cov, up_W, up_b, hf, hb);

    for (int i = 0; i < 8; ++i) {
        int dil = 1 << i;
        int tb  = T0 + 2 * dil;
        int M   = (T_TOTAL - tb) * NB;
        int mtiles = (M + 127) / 128;
        hipLaunchKernelGGL(gemm_gate, dim3(mtiles, 4), dim3(256), 0, stream,
                           hb, gated, wT + (size_t)i * 512 * 512,
                           dil_b + (size_t)i * 512, tb, dil, M);
        hipLaunchKernelGGL(gemm_skip, dim3(mtiles, 4), dim3(256), 0, stream,
                           gated, w2 + (size_t)i * 512 * 256, hf, hb, skip,
                           skip_b + (size_t)i * 512, tb, M, i == 0 ? 1 : 0);
    }
    hipLaunchKernelGGL(final_kernel, dim3(LOUT * NB / 4), dim3(256), 0, stream,
                       skip, loc_W, loc_b, proj_W, proj_b, out);
}

// Round 3
// 187.934 us; speedup vs baseline: 3.6528x; 1.6891x over previous
//
#include <hip/hip_runtime.h>
#include <math.h>
#include <stdint.h>

#define T_TOTAL 2048
#define NB 16
#define D 256
#define T0 1696      // h buffer covers t in [1696, 2047]
#define TBUF 352
#define TSKIP 1952   // skip needed for t in [1952, 2047]
#define LOUT 96

typedef __bf16 bf16x8 __attribute__((ext_vector_type(8)));
typedef float f32x4 __attribute__((ext_vector_type(4)));

__device__ __forceinline__ void gload_lds16(const void* src, void* lds_dst) {
    auto g = (const __attribute__((address_space(1))) void*)(uintptr_t)src;
    auto l = (__attribute__((address_space(3))) void*)(uintptr_t)(
                 (uint32_t)(uintptr_t)lds_dst);
    __builtin_amdgcn_global_load_lds(g, l, 16, 0, 0);
}

// ---------------- weight prep: wT[i][co][k]=dil_w[i][co][ci][tap] (k=tap*256+ci)
//                  w2[i][co][ci]=skip_w[i][co][ci]   (both bf16)
__global__ void prep_w(const float* __restrict__ dil_w,
                       const float* __restrict__ skip_w,
                       __bf16* __restrict__ wT, __bf16* __restrict__ w2)
{
    int n = blockIdx.x * 256 + threadIdx.x;
    if (n < 8 * 512 * 512) {
        int i = n >> 18;
        int r = n & 262143;
        int co = r >> 9, k = r & 511;
        wT[n] = (__bf16)dil_w[(((size_t)(i << 9) + co) * 256 + (k & 255)) * 2 + (k >> 8)];
    } else {
        int n2 = n - 8 * 512 * 512;
        if (n2 < 8 * 512 * 256) w2[n2] = (__bf16)skip_w[n2];
    }
}

// ---------------- up-projection
__global__ void up_kernel(const float* __restrict__ x_lag,
                          const float* __restrict__ x_cov,
                          const float* __restrict__ up_W,
                          const float* __restrict__ up_b,
                          float* __restrict__ hf, __bf16* __restrict__ hb)
{
    int bid = blockIdx.x;          // 0 .. TBUF*NB-1
    int tt  = bid >> 4;
    int b   = bid & 15;
    int t   = T0 + tt;
    int c   = threadIdx.x;         // 0..255
    float acc = up_b[c] + x_lag[t * NB + b] * up_W[c];
    const float* cov = &x_cov[(t * NB + b) * 7];
    #pragma unroll
    for (int j = 0; j < 7; ++j)
        acc += cov[j] * up_W[(j + 1) * D + c];
    size_t idx = ((size_t)bid << 8) + c;
    hf[idx] = acc;
    hb[idx] = (__bf16)acc;
}

// ---------------- GEMM1 (MFMA, dbuf): z=[h(t-dil),h(t)]@wT^T ; gated=tanh*sig
__global__ __launch_bounds__(256, 3) void gemm_gate(
    const __bf16* __restrict__ hb, __bf16* __restrict__ gated,
    const __bf16* __restrict__ wTl, const float* __restrict__ bias,
    int tb, int dil, int M)
{
    __shared__ __align__(16) unsigned char lds[49152];
    const int tid = threadIdx.x;
    const int lane = tid & 63, wid = tid >> 6;
    const int wm = wid >> 1, wn = wid & 1;
    const int m0 = blockIdx.x << 6;
    const int cb = blockIdx.y << 6;
    const int lr = lane >> 3;
    const int swzc = ((lane & 7) ^ lr) << 3;   // elems
    const int l15 = lane & 15, l4 = lane >> 4;
    const int roff1 = (tb - T0) * 16;
    const int roff0 = roff1 - dil * 16;

    f32x4 accf[2][2] = {}; f32x4 accg[2][2] = {};

    auto stage = [&](int t, int buf) {
        const int k0 = t << 6;
        const int ci0 = k0 & 255;
        const int roff = (k0 < 256) ? roff0 : roff1;
        unsigned char* base = lds + buf * 24576;
        #pragma unroll
        for (int j = 0; j < 2; ++j) {
            int qa = (wid << 1) + j;
            int m = m0 + (qa << 3) + lr; if (m >= M) m = M - 1;
            gload_lds16(hb + (size_t)(m + roff) * 256 + ci0 + swzc,
                        base + (qa << 10));
        }
        #pragma unroll
        for (int j = 0; j < 2; ++j) {
            int qb = (wid << 1) + j;
            gload_lds16(wTl + (size_t)(cb + (qb << 3) + lr) * 512 + k0 + swzc,
                        base + 8192 + (qb << 10));
            gload_lds16(wTl + (size_t)(cb + 256 + (qb << 3) + lr) * 512 + k0 + swzc,
                        base + 16384 + (qb << 10));
        }
    };

    stage(0, 0);
    for (int t = 0; t < 8; ++t) {
        const int buf = t & 1;
        if (t < 7) {
            stage(t + 1, buf ^ 1);
            asm volatile("s_waitcnt vmcnt(6)" ::: "memory");
        } else {
            asm volatile("s_waitcnt vmcnt(0)" ::: "memory");
        }
        __builtin_amdgcn_s_barrier();
        const unsigned char* base = lds + buf * 24576;
        #pragma unroll
        for (int ks = 0; ks < 2; ++ks) {
            const int kb = (ks << 6) + (l4 << 4);
            bf16x8 av[2], bfv[2], bgv[2];
            #pragma unroll
            for (int fm = 0; fm < 2; ++fm) {
                int r = (wm << 5) + (fm << 4) + l15;
                av[fm] = *(const bf16x8*)(base + r * 128 + (kb ^ ((r & 7) << 4)));
            }
            #pragma unroll
            for (int fn = 0; fn < 2; ++fn) {
                int n = (wn << 5) + (fn << 4) + l15;
                int o = n * 128 + (kb ^ ((n & 7) << 4));
                bfv[fn] = *(const bf16x8*)(base + 8192 + o);
                bgv[fn] = *(const bf16x8*)(base + 16384 + o);
            }
            #pragma unroll
            for (int fm = 0; fm < 2; ++fm)
                #pragma unroll
                for (int fn = 0; fn < 2; ++fn) {
                    accf[fm][fn] = __builtin_amdgcn_mfma_f32_16x16x32_bf16(
                        av[fm], bfv[fn], accf[fm][fn], 0, 0, 0);
                    accg[fm][fn] = __builtin_amdgcn_mfma_f32_16x16x32_bf16(
                        av[fm], bgv[fn], accg[fm][fn], 0, 0, 0);
                }
        }
        __builtin_amdgcn_s_barrier();
    }
    #pragma unroll
    for (int fm = 0; fm < 2; ++fm) {
        #pragma unroll
        for (int fn = 0; fn < 2; ++fn) {
            int c = cb + (wn << 5) + (fn << 4) + l15;
            float bfb = bias[c], bgb = bias[c + 256];
            #pragma unroll
            for (int r = 0; r < 4; ++r) {
                int m = m0 + (wm << 5) + (fm << 4) + (l4 << 2) + r;
                if (m < M) {
                    float fv = accf[fm][fn][r] + bfb;
                    float gv = accg[fm][fn][r] + bgb;
                    float th = 2.0f / (1.0f + __expf(-2.0f * fv)) - 1.0f;
                    float sg = 1.0f / (1.0f + __expf(-gv));
                    gated[(size_t)m * 256 + c] = (__bf16)(th * sg);
                }
            }
        }
    }
}

// ---------------- GEMM2 (MFMA, dbuf): z2=gated@w2^T ; h+=z2[:,:256]; skip+=rest
__global__ __launch_bounds__(256, 3) void gemm_skip(
    const __bf16* __restrict__ gated, const __bf16* __restrict__ w2l,
    float* __restrict__ hf, __bf16* __restrict__ hb,
    float* __restrict__ skip, const float* __restrict__ bias,
    int tb, int M, int first)
{
    __shared__ __align__(16) unsigned char lds[49152];
    const int tid = threadIdx.x;
    const int lane = tid & 63, wid = tid >> 6;
    const int wm = wid >> 1, wn = wid & 1;
    const int m0 = blockIdx.x << 6;
    const int cb = blockIdx.y << 6;
    const int lr = lane >> 3;
    const int swzc = ((lane & 7) ^ lr) << 3;
    const int l15 = lane & 15, l4 = lane >> 4;

    f32x4 acch[2][2] = {}; f32x4 accs[2][2] = {};

    auto stage = [&](int t, int buf) {
        const int k0 = t << 6;
        unsigned char* base = lds + buf * 24576;
        #pragma unroll
        for (int j = 0; j < 2; ++j) {
            int qa = (wid << 1) + j;
            int m = m0 + (qa << 3) + lr; if (m >= M) m = M - 1;
            gload_lds16(gated + (size_t)m * 256 + k0 + swzc,
                        base + (qa << 10));
        }
        #pragma unroll
        for (int j = 0; j < 2; ++j) {
            int qb = (wid << 1) + j;
            gload_lds16(w2l + (size_t)(cb + (qb << 3) + lr) * 256 + k0 + swzc,
                        base + 8192 + (qb << 10));
            gload_lds16(w2l + (size_t)(cb + 256 + (qb << 3) + lr) * 256 + k0 + swzc,
                        base + 16384 + (qb << 10));
        }
    };

    stage(0, 0);
    for (int t = 0; t < 4; ++t) {
        const int buf = t & 1;
        if (t < 3) {
            stage(t + 1, buf ^ 1);
            asm volatile("s_waitcnt vmcnt(6)" ::: "memory");
        } else {
            asm volatile("s_waitcnt vmcnt(0)" ::: "memory");
        }
        __builtin_amdgcn_s_barrier();
        const unsigned char* base = lds + buf * 24576;
        #pragma unroll
        for (int ks = 0; ks < 2; ++ks) {
            const int kb = (ks << 6) + (l4 << 4);
            bf16x8 av[2], bhv[2], bsv[2];
            #pragma unroll
            for (int fm = 0; fm < 2; ++fm) {
                int r = (wm << 5) + (fm << 4) + l15;
                av[fm] = *(const bf16x8*)(base + r * 128 + (kb ^ ((r & 7) << 4)));
            }
            #pragma unroll
            for (int fn = 0; fn < 2; ++fn) {
                int n = (wn << 5) + (fn << 4) + l15;
                int o = n * 128 + (kb ^ ((n & 7) << 4));
                bhv[fn] = *(const bf16x8*)(base + 8192 + o);
                bsv[fn] = *(const bf16x8*)(base + 16384 + o);
            }
            #pragma unroll
            for (int fm = 0; fm < 2; ++fm)
                #pragma unroll
                for (int fn = 0; fn < 2; ++fn) {
                    acch[fm][fn] = __builtin_amdgcn_mfma_f32_16x16x32_bf16(
                        av[fm], bhv[fn], acch[fm][fn], 0, 0, 0);
                    accs[fm][fn] = __builtin_amdgcn_mfma_f32_16x16x32_bf16(
                        av[fm], bsv[fn], accs[fm][fn], 0, 0, 0);
                }
        }
        __builtin_amdgcn_s_barrier();
    }
    const int roff = (tb - T0) * 16;
    const int ms0 = (TSKIP - tb) * 16;
    const int soff = (tb - TSKIP) * 16;
    #pragma unroll
    for (int fm = 0; fm < 2; ++fm) {
        #pragma unroll
        for (int fn = 0; fn < 2; ++fn) {
            int c = cb + (wn << 5) + (fn << 4) + l15;
            float bhb = bias[c], bsb = bias[c + 256];
            #pragma unroll
            for (int r = 0; r < 4; ++r) {
                int m = m0 + (wm << 5) + (fm << 4) + (l4 << 2) + r;
                if (m < M) {
                    size_t hi = (size_t)(m + roff) * 256 + c;
                    float hv = hf[hi] + acch[fm][fn][r] + bhb;
                    hf[hi] = hv;
                    hb[hi] = (__bf16)hv;
                    if (m >= ms0) {
                        size_t si = (size_t)(m + soff) * 256 + c;
                        float sv = accs[fm][fn][r] + bsb;
                        if (!first) sv += skip[si];
                        skip[si] = sv;
                    }
                }
            }
        }
    }
}

// ---------------- final
__global__ void final_kernel(const float* __restrict__ skip,
                             const float* __restrict__ loc_W,
                             const float* __restrict__ loc_b,
                             const float* __restrict__ proj_W,
                             const float* __restrict__ proj_b,
                             float* __restrict__ out)
{
    int tid = threadIdx.x;
    int w = tid >> 6, lane = tid & 63;
    int o = blockIdx.x * 4 + w;          // o = l*16 + b
    int l = o >> 4, b = o & 15;
    float4 s4 = *(const float4*)&skip[((size_t)o << 8) + (lane << 2)];
    float4 w4 = *(const float4*)&loc_W[lane << 2];
    float s = s4.x * w4.x + s4.y * w4.y + s4.z * w4.z + s4.w * w4.w;
    #pragma unroll
    for (int off = 32; off; off >>= 1) s += __shfl_down(s, off);
    if (lane == 0)
        out[b * LOUT + l] = (s + loc_b[0]) * proj_W[0] + proj_b[0];
}

extern "C" void kernel_launch(void* const* d_in, const int* in_sizes, int n_in,
                              void* d_out, int out_size, void* d_ws, size_t ws_size,
                              hipStream_t stream)
{
    const float* x_lag  = (const float*)d_in[0];
    const float* x_cov  = (const float*)d_in[1];
    const float* up_W   = (const float*)d_in[2];
    const float* up_b   = (const float*)d_in[3];
    const float* dil_w  = (const float*)d_in[4];
    const float* dil_b  = (const float*)d_in[5];
    const float* skip_w = (const float*)d_in[6];
    const float* skip_b = (const float*)d_in[7];
    const float* loc_W  = (const float*)d_in[8];
    const float* loc_b  = (const float*)d_in[9];
    const float* proj_W = (const float*)d_in[10];
    const float* proj_b = (const float*)d_in[11];
    float* out = (float*)d_out;

    unsigned char* ws = (unsigned char*)d_ws;
    float*  hf   = (float*)ws;                                   // 5632*256 f32
    __bf16* hb   = (__bf16*)(ws + 5767168);                      // 5632*256 bf16
    __bf16* gated= (__bf16*)(ws + 5767168 + 2883584);            // 5632*256 bf16
    float*  skip = (float*)(ws + 5767168 + 2 * 2883584);         // 1536*256 f32
    __bf16* wT   = (__bf16*)(ws + 5767168 + 2 * 2883584 + 1572864);   // 8*512*512
    __bf16* w2   = (__bf16*)((unsigned char*)wT + 4194304);      // 8*512*256

    hipLaunchKernelGGL(prep_w, dim3(12288), dim3(256), 0, stream,
                       dil_w, skip_w, wT, w2);
    hipLaunchKernelGGL(up_kernel, dim3(TBUF * NB), dim3(D), 0, stream,
                       x_lag, x_cov, up_W, up_b, hf, hb);

    for (int i = 0; i < 8; ++i) {
        int dil = 1 << i;
        int tb  = T0 + 2 * dil;
        int M   = (T_TOTAL - tb) * NB;
        int mtiles = (M + 63) / 64;
        hipLaunchKernelGGL(gemm_gate, dim3(mtiles, 4), dim3(256), 0, stream,
                           hb, gated, wT + (size_t)i * 512 * 512,
                           dil_b + (size_t)i * 512, tb, dil, M);
        hipLaunchKernelGGL(gemm_skip, dim3(mtiles, 4), dim3(256), 0, stream,
                           gated, w2 + (size_t)i * 512 * 256, hf, hb, skip,
                           skip_b + (size_t)i * 512, tb, M, i == 0 ? 1 : 0);
    }
    hipLaunchKernelGGL(final_kernel, dim3(LOUT * NB / 4), dim3(256), 0, stream,
                       skip, loc_W, loc_b, proj_W, proj_b, out);
}